// Round 11
// baseline (387.274 us; speedup 1.0000x reference)
//
#include <hip/hip_runtime.h>

#define BB 4096
#define TT 512
#define HH 32

typedef _Float16 half8 __attribute__((ext_vector_type(8)));  // MFMA A/B frag (4 VGPRs)
typedef _Float16 h2    __attribute__((ext_vector_type(2)));  // packed f16 pair
typedef float    f32x4 __attribute__((ext_vector_type(4)));  // MFMA C/D

#define MFMA16F(a, b, c) __builtin_amdgcn_mfma_f32_16x16x32_f16((a), (b), (c), 0, 0, 0)

union frag_u { half8 h8; h2 p[4]; };

// v_cvt_pkrtz_f16_f32 returns a __fp16 ext-vector; bit-cast to _Float16 vector.
__device__ __forceinline__ h2 pkrtz(float a, float b) {
    auto r = __builtin_amdgcn_cvt_pkrtz(a, b);
    union { decltype(r) i; h2 o; } u;
    u.i = r;
    return u.o;
}

// tanh(v) ~= v * P(v^2), quintic P, Chebyshev fit on |v|<=2.75 (max err ~2e-3).
// Packed f16, full-rate. (r7-verified: absmax 0.0039.)
__device__ __forceinline__ h2 tanh_h2(h2 v) {
    const h2 LO = {(_Float16)(-2.75f), (_Float16)(-2.75f)};
    const h2 HI = {(_Float16)(2.75f), (_Float16)(2.75f)};
    const h2 C0 = {(_Float16)(0.9976293f), (_Float16)(0.9976293f)};
    const h2 C1 = {(_Float16)(-0.3098016f), (_Float16)(-0.3098016f)};
    const h2 C2 = {(_Float16)(0.0889744f), (_Float16)(0.0889744f)};
    const h2 C3 = {(_Float16)(-0.0163448f), (_Float16)(-0.0163448f)};
    const h2 C4 = {(_Float16)(0.0016113f), (_Float16)(0.0016113f)};
    const h2 C5 = {(_Float16)(-0.00006405f), (_Float16)(-0.00006405f)};
    v = __builtin_elementwise_min(v, HI);
    v = __builtin_elementwise_max(v, LO);
    h2 u = v * v;
    h2 w = u * u;
    h2 p01 = __builtin_elementwise_fma(u, C1, C0);
    h2 p23 = __builtin_elementwise_fma(u, C3, C2);
    h2 p45 = __builtin_elementwise_fma(u, C5, C4);
    h2 qq = __builtin_elementwise_fma(w, p45, p23);
    h2 t = __builtin_elementwise_fma(w, qq, p01);
    return v * t;
}

// D = W @ H^T per step, M = h'-rows (2 tiles of 16), N = 16 batches.
// Row permutation pi_t(m) = 8*(m>>2) + (m&3) + 4t makes the C/D output layout
// equal the B-operand layout of the next matvec -> recurrence stays in registers.
//
// Round-11: TWO independent 16-batch tiles (a/b) interleaved in ONE wave.
// Calibrated r7 PMC (VALUBusy 14.8% == ~111 insts/step at the gfx94x 4-cyc
// accounting) shows the active SIMD is only ~30% issue-busy; ~70% is
// MFMA<->VALU dependency-boundary stall. Two chains' issue (2 x ~220 cyc)
// still fits under the 750-cyc wall, so tile b's work fills tile a's stalls.
// Named variables only (r4's NT-array version likely spilled); math per
// batch is exactly r7's (passed, absmax 0.0039, stable).
__global__ __launch_bounds__(64, 1) void rnn2_mfma(
    const float* __restrict__ x,      // [B, T]
    const float* __restrict__ hstate, // [2, B, H]
    const float* __restrict__ Wih0,   // [H, 1]
    const float* __restrict__ Whh0,   // [H, H]
    const float* __restrict__ bih0,   // [H]
    const float* __restrict__ bhh0,   // [H]
    const float* __restrict__ Wih1,   // [H, H]
    const float* __restrict__ Whh1,   // [H, H]
    const float* __restrict__ bih1,   // [H]
    const float* __restrict__ bhh1,   // [H]
    const float* __restrict__ Wfc,    // [1, H]
    const float* __restrict__ bfc,    // [1]
    float* __restrict__ out)          // [B] pred ++ [2,B,H] h_new
{
    const int l = threadIdx.x;   // 0..63
    const int q = l >> 4;        // lane quad -> k-offset 8q
    const int n = l & 15;        // batch-in-tile / matrix row m
    const int ba = blockIdx.x * 32 + n;        // tile a batch
    const int bb = ba + 16;                    // tile b batch

    // ---- shared weight A-fragments (f16), permuted rows ----
    const int r0 = 8 * (n >> 2) + (n & 3);
    half8 A0[2], A1i[2], A1h[2];
#pragma unroll
    for (int t = 0; t < 2; ++t) {
        const int row = r0 + 4 * t;
        const float* p0 = Whh0 + row * HH + q * 8;
        const float* p1 = Wih1 + row * HH + q * 8;
        const float* p2 = Whh1 + row * HH + q * 8;
        frag_u f0, f1, f2;
#pragma unroll
        for (int jj = 0; jj < 4; ++jj) {
            f0.p[jj] = h2{(_Float16)p0[2 * jj], (_Float16)p0[2 * jj + 1]};
            f1.p[jj] = h2{(_Float16)p1[2 * jj], (_Float16)p1[2 * jj + 1]};
            f2.p[jj] = h2{(_Float16)p2[2 * jj], (_Float16)p2[2 * jj + 1]};
        }
        A0[t] = f0.h8; A1i[t] = f1.h8; A1h[t] = f2.h8;
    }

    // ---- shared per-lane constants over j=0..7 (h' = 8q + j) ----
    float wxs[8], b0s[8], wfc8[8];
#pragma unroll
    for (int j = 0; j < 8; ++j) {
        const int hh = 8 * q + j;
        wxs[j]  = Wih0[hh];
        b0s[j]  = bih0[hh] + bhh0[hh];
        wfc8[j] = Wfc[hh];
    }
    f32x4 c1t0, c1t1;   // layer-1 bias, rides as C of the Whh1 MFMA
#pragma unroll
    for (int r = 0; r < 4; ++r) {
        c1t0[r] = bih1[8 * q + r] + bhh1[8 * q + r];
        c1t1[r] = bih1[8 * q + 4 + r] + bhh1[8 * q + 4 + r];
    }

    // ---- initial h state as f16 B-fragments (both tiles) ----
    frag_u hb0a, hb1a, hb0b, hb1b;
    {
        const float* pa0 = hstate + ba * HH + 8 * q;
        const float* pa1 = hstate + BB * HH + ba * HH + 8 * q;
        const float* pb0 = hstate + bb * HH + 8 * q;
        const float* pb1 = hstate + BB * HH + bb * HH + 8 * q;
#pragma unroll
        for (int jj = 0; jj < 4; ++jj) {
            hb0a.p[jj] = h2{(_Float16)pa0[2 * jj], (_Float16)pa0[2 * jj + 1]};
            hb1a.p[jj] = h2{(_Float16)pa1[2 * jj], (_Float16)pa1[2 * jj + 1]};
            hb0b.p[jj] = h2{(_Float16)pb0[2 * jj], (_Float16)pb0[2 * jj + 1]};
            hb1b.p[jj] = h2{(_Float16)pb1[2 * jj], (_Float16)pb1[2 * jj + 1]};
        }
    }

    f32x4 dbp0a, dbp1a, dbp0b, dbp1b;   // pending b1 + Whh1 . h1(s-2)

    const float4* xpa = (const float4*)(x + (size_t)ba * TT);
    const float4* xpb = (const float4*)(x + (size_t)bb * TT);
    float4 xca = xpa[0];
    float4 xcb = xpb[0];

    // ---- prologue: layer-0 step 0 + pending db, both tiles ----
    {
        f32x4 c00a, c01a, c00b, c01b;
#pragma unroll
        for (int r = 0; r < 4; ++r) {
            c00a[r] = fmaf(wxs[r], xca.x, b0s[r]);
            c01a[r] = fmaf(wxs[4 + r], xca.x, b0s[4 + r]);
            c00b[r] = fmaf(wxs[r], xcb.x, b0s[r]);
            c01b[r] = fmaf(wxs[4 + r], xcb.x, b0s[4 + r]);
        }
        f32x4 d00a = MFMA16F(A0[0], hb0a.h8, c00a);
        f32x4 d00b = MFMA16F(A0[0], hb0b.h8, c00b);
        f32x4 d01a = MFMA16F(A0[1], hb0a.h8, c01a);
        f32x4 d01b = MFMA16F(A0[1], hb0b.h8, c01b);
        dbp0a = MFMA16F(A1h[0], hb1a.h8, c1t0);
        dbp0b = MFMA16F(A1h[0], hb1b.h8, c1t0);
        dbp1a = MFMA16F(A1h[1], hb1a.h8, c1t1);
        dbp1b = MFMA16F(A1h[1], hb1b.h8, c1t1);
        hb0a.p[0] = tanh_h2(pkrtz(d00a[0], d00a[1]));
        hb0a.p[1] = tanh_h2(pkrtz(d00a[2], d00a[3]));
        hb0a.p[2] = tanh_h2(pkrtz(d01a[0], d01a[1]));
        hb0a.p[3] = tanh_h2(pkrtz(d01a[2], d01a[3]));
        hb0b.p[0] = tanh_h2(pkrtz(d00b[0], d00b[1]));
        hb0b.p[1] = tanh_h2(pkrtz(d00b[2], d00b[3]));
        hb0b.p[2] = tanh_h2(pkrtz(d01b[0], d01b[1]));
        hb0b.p[3] = tanh_h2(pkrtz(d01b[2], d01b[3]));
    }

    // STEP2: r7's STEP for both tiles, instruction-interleaved.
#define STEP2(XTA, XTB)                                                       \
    {                                                                         \
        f32x4 d10a = MFMA16F(A1i[0], hb0a.h8, dbp0a);                         \
        f32x4 d10b = MFMA16F(A1i[0], hb0b.h8, dbp0b);                         \
        f32x4 d11a = MFMA16F(A1i[1], hb0a.h8, dbp1a);                         \
        f32x4 d11b = MFMA16F(A1i[1], hb0b.h8, dbp1b);                         \
        f32x4 c00a, c01a, c00b, c01b;                                         \
        _Pragma("unroll")                                                     \
        for (int r = 0; r < 4; ++r) {                                         \
            c00a[r] = fmaf(wxs[r], (XTA), b0s[r]);                            \
            c01a[r] = fmaf(wxs[4 + r], (XTA), b0s[4 + r]);                    \
            c00b[r] = fmaf(wxs[r], (XTB), b0s[r]);                            \
            c01b[r] = fmaf(wxs[4 + r], (XTB), b0s[4 + r]);                    \
        }                                                                     \
        f32x4 d00a = MFMA16F(A0[0], hb0a.h8, c00a);                           \
        f32x4 d00b = MFMA16F(A0[0], hb0b.h8, c00b);                           \
        f32x4 d01a = MFMA16F(A0[1], hb0a.h8, c01a);                           \
        f32x4 d01b = MFMA16F(A0[1], hb0b.h8, c01b);                           \
        hb1a.p[0] = tanh_h2(pkrtz(d10a[0], d10a[1]));                         \
        hb1b.p[0] = tanh_h2(pkrtz(d10b[0], d10b[1]));                         \
        hb1a.p[1] = tanh_h2(pkrtz(d10a[2], d10a[3]));                         \
        hb1b.p[1] = tanh_h2(pkrtz(d10b[2], d10b[3]));                         \
        hb1a.p[2] = tanh_h2(pkrtz(d11a[0], d11a[1]));                         \
        hb1b.p[2] = tanh_h2(pkrtz(d11b[0], d11b[1]));                         \
        hb1a.p[3] = tanh_h2(pkrtz(d11a[2], d11a[3]));                         \
        hb1b.p[3] = tanh_h2(pkrtz(d11b[2], d11b[3]));                         \
        dbp0a = MFMA16F(A1h[0], hb1a.h8, c1t0);                               \
        dbp0b = MFMA16F(A1h[0], hb1b.h8, c1t0);                               \
        dbp1a = MFMA16F(A1h[1], hb1a.h8, c1t1);                               \
        dbp1b = MFMA16F(A1h[1], hb1b.h8, c1t1);                               \
        hb0a.p[0] = tanh_h2(pkrtz(d00a[0], d00a[1]));                         \
        hb0b.p[0] = tanh_h2(pkrtz(d00b[0], d00b[1]));                         \
        hb0a.p[1] = tanh_h2(pkrtz(d00a[2], d00a[3]));                         \
        hb0b.p[1] = tanh_h2(pkrtz(d00b[2], d00b[3]));                         \
        hb0a.p[2] = tanh_h2(pkrtz(d01a[0], d01a[1]));                         \
        hb0b.p[2] = tanh_h2(pkrtz(d01b[0], d01b[1]));                         \
        hb0a.p[3] = tanh_h2(pkrtz(d01a[2], d01a[3]));                         \
        hb0b.p[3] = tanh_h2(pkrtz(d01b[2], d01b[3]));                         \
    }

    // main loop: k = 0..126 handles s = 4k+1 .. 4k+4
    for (int k = 0; k < TT / 4 - 1; ++k) {
        float4 xna = xpa[k + 1];
        float4 xnb = xpb[k + 1];
        STEP2(xca.y, xcb.y);
        STEP2(xca.z, xcb.z);
        STEP2(xca.w, xcb.w);
        STEP2(xna.x, xnb.x);
        xca = xna;
        xcb = xnb;
    }
    // s = 509, 510, 511
    STEP2(xca.y, xcb.y);
    STEP2(xca.z, xcb.z);
    STEP2(xca.w, xcb.w);

    // tail: layer-1 step 511, both tiles
    {
        f32x4 d10a = MFMA16F(A1i[0], hb0a.h8, dbp0a);
        f32x4 d10b = MFMA16F(A1i[0], hb0b.h8, dbp0b);
        f32x4 d11a = MFMA16F(A1i[1], hb0a.h8, dbp1a);
        f32x4 d11b = MFMA16F(A1i[1], hb0b.h8, dbp1b);
        hb1a.p[0] = tanh_h2(pkrtz(d10a[0], d10a[1]));
        hb1a.p[1] = tanh_h2(pkrtz(d10a[2], d10a[3]));
        hb1a.p[2] = tanh_h2(pkrtz(d11a[0], d11a[1]));
        hb1a.p[3] = tanh_h2(pkrtz(d11a[2], d11a[3]));
        hb1b.p[0] = tanh_h2(pkrtz(d10b[0], d10b[1]));
        hb1b.p[1] = tanh_h2(pkrtz(d10b[2], d10b[3]));
        hb1b.p[2] = tanh_h2(pkrtz(d11b[0], d11b[1]));
        hb1b.p[3] = tanh_h2(pkrtz(d11b[2], d11b[3]));
    }

    // ---- epilogue (both tiles) ----
    const float bfc0 = bfc[0];
    {
        float hf0[8], hf1[8];
#pragma unroll
        for (int jj = 0; jj < 4; ++jj) {
            hf0[2 * jj]     = (float)hb0a.p[jj].x;
            hf0[2 * jj + 1] = (float)hb0a.p[jj].y;
            hf1[2 * jj]     = (float)hb1a.p[jj].x;
            hf1[2 * jj + 1] = (float)hb1a.p[jj].y;
        }
        float p = 0.f;
#pragma unroll
        for (int j = 0; j < 8; ++j) p = fmaf(wfc8[j], hf1[j], p);
        p += __shfl_xor(p, 16);
        p += __shfl_xor(p, 32);
        if (q == 0) out[ba] = p + bfc0;
#pragma unroll
        for (int j = 0; j < 8; ++j) {
            out[BB + ba * HH + 8 * q + j]           = hf0[j];
            out[BB + BB * HH + ba * HH + 8 * q + j] = hf1[j];
        }
    }
    {
        float hf0[8], hf1[8];
#pragma unroll
        for (int jj = 0; jj < 4; ++jj) {
            hf0[2 * jj]     = (float)hb0b.p[jj].x;
            hf0[2 * jj + 1] = (float)hb0b.p[jj].y;
            hf1[2 * jj]     = (float)hb1b.p[jj].x;
            hf1[2 * jj + 1] = (float)hb1b.p[jj].y;
        }
        float p = 0.f;
#pragma unroll
        for (int j = 0; j < 8; ++j) p = fmaf(wfc8[j], hf1[j], p);
        p += __shfl_xor(p, 16);
        p += __shfl_xor(p, 32);
        if (q == 0) out[bb] = p + bfc0;
#pragma unroll
        for (int j = 0; j < 8; ++j) {
            out[BB + bb * HH + 8 * q + j]           = hf0[j];
            out[BB + BB * HH + bb * HH + 8 * q + j] = hf1[j];
        }
    }
}

extern "C" void kernel_launch(void* const* d_in, const int* in_sizes, int n_in,
                              void* d_out, int out_size, void* d_ws, size_t ws_size,
                              hipStream_t stream) {
    const float* x      = (const float*)d_in[0];
    const float* hstate = (const float*)d_in[1];
    const float* Wih0   = (const float*)d_in[2];
    const float* Whh0   = (const float*)d_in[3];
    const float* bih0   = (const float*)d_in[4];
    const float* bhh0   = (const float*)d_in[5];
    const float* Wih1   = (const float*)d_in[6];
    const float* Whh1   = (const float*)d_in[7];
    const float* bih1   = (const float*)d_in[8];
    const float* bhh1   = (const float*)d_in[9];
    const float* Wfc    = (const float*)d_in[10];
    const float* bfc    = (const float*)d_in[11];
    float* out = (float*)d_out;

    dim3 grid(BB / 32);  // 128 blocks x 1 wave, two 16-batch tiles each
    dim3 block(64);
    hipLaunchKernelGGL(rnn2_mfma, grid, block, 0, stream,
                       x, hstate, Wih0, Whh0, bih0, bhh0,
                       Wih1, Whh1, bih1, bhh1, Wfc, bfc, out);
}

// Round 12
// 224.390 us; speedup vs baseline: 1.7259x; 1.7259x over previous
//
#include <hip/hip_runtime.h>
#include <hip/hip_fp16.h>

#define BB 4096
#define TT 512
#define HH 32

typedef _Float16 half8 __attribute__((ext_vector_type(8)));  // MFMA A/B frag (4 VGPRs)
typedef _Float16 h2    __attribute__((ext_vector_type(2)));  // packed f16 pair
typedef float    f32x4 __attribute__((ext_vector_type(4)));  // MFMA C/D

#define MFMA16F(a, b, c) __builtin_amdgcn_mfma_f32_16x16x32_f16((a), (b), (c), 0, 0, 0)

union frag_u { half8 h8; h2 p[4]; };
union h2u { __half2 h; h2 v; };

// v_cvt_pkrtz_f16_f32 returns a __fp16 ext-vector; bit-cast to _Float16 vector.
__device__ __forceinline__ h2 pkrtz(float a, float b) {
    auto r = __builtin_amdgcn_cvt_pkrtz(a, b);
    union { decltype(r) i; h2 o; } u;
    u.i = r;
    return u.o;
}

// tanh on two MFMA f32 outputs: clamp via v_med3_f32 (1 inst/value), pack,
// then quintic v*P(v^2) entirely in __half2 intrinsics, which map 1:1 to
// v_pk_{mul,fma}_f16. Round-11 calibration: active SIMD is ~60% VALU-busy
// (~440 cyc/step) vs ~200 cyc for a truly-packed count -- forcing packed ops
// through __hfma2/__hmul2 is the isolated change this round tests.
__device__ __forceinline__ h2 tanh_pk(float x0, float x1) {
    x0 = __builtin_amdgcn_fmed3f(x0, -2.75f, 2.75f);
    x1 = __builtin_amdgcn_fmed3f(x1, -2.75f, 2.75f);
    h2u v; v.v = pkrtz(x0, x1);
    const __half2 C0 = __float2half2_rn(0.9976293f);
    const __half2 C1 = __float2half2_rn(-0.3098016f);
    const __half2 C2 = __float2half2_rn(0.0889744f);
    const __half2 C3 = __float2half2_rn(-0.0163448f);
    const __half2 C4 = __float2half2_rn(0.0016113f);
    const __half2 C5 = __float2half2_rn(-0.00006405f);
    __half2 u = __hmul2(v.h, v.h);
    __half2 w = __hmul2(u, u);
    __half2 p01 = __hfma2(u, C1, C0);
    __half2 p23 = __hfma2(u, C3, C2);
    __half2 p45 = __hfma2(u, C5, C4);
    __half2 qq = __hfma2(w, p45, p23);
    __half2 t = __hfma2(w, qq, p01);
    h2u r; r.h = __hmul2(v.h, t);
    return r.v;
}

// D = W @ H^T per step, M = h'-rows (2 tiles of 16), N = 16 batches.
// Row permutation pi_t(m) = 8*(m>>2) + (m&3) + 4t makes the C/D output layout
// equal the B-operand layout of the next matvec -> recurrence stays in registers.
// Structure identical to round 7 (best known: 159us, absmax 0.0039, stable);
// only the tanh implementation changed.
__global__ __launch_bounds__(64) void rnn2_mfma(
    const float* __restrict__ x,      // [B, T]
    const float* __restrict__ hstate, // [2, B, H]
    const float* __restrict__ Wih0,   // [H, 1]
    const float* __restrict__ Whh0,   // [H, H]
    const float* __restrict__ bih0,   // [H]
    const float* __restrict__ bhh0,   // [H]
    const float* __restrict__ Wih1,   // [H, H]
    const float* __restrict__ Whh1,   // [H, H]
    const float* __restrict__ bih1,   // [H]
    const float* __restrict__ bhh1,   // [H]
    const float* __restrict__ Wfc,    // [1, H]
    const float* __restrict__ bfc,    // [1]
    float* __restrict__ out)          // [B] pred ++ [2,B,H] h_new
{
    const int l = threadIdx.x;   // 0..63
    const int q = l >> 4;        // lane quad -> k-offset 8q
    const int n = l & 15;        // batch-in-tile / matrix row m
    const int b = blockIdx.x * 16 + n;

    // ---- weight A-fragments (f16), permuted rows ----
    const int r0 = 8 * (n >> 2) + (n & 3);
    half8 A0[2], A1i[2], A1h[2];
#pragma unroll
    for (int t = 0; t < 2; ++t) {
        const int row = r0 + 4 * t;
        const float* p0 = Whh0 + row * HH + q * 8;
        const float* p1 = Wih1 + row * HH + q * 8;
        const float* p2 = Whh1 + row * HH + q * 8;
        frag_u f0, f1, f2;
#pragma unroll
        for (int jj = 0; jj < 4; ++jj) {
            f0.p[jj] = h2{(_Float16)p0[2 * jj], (_Float16)p0[2 * jj + 1]};
            f1.p[jj] = h2{(_Float16)p1[2 * jj], (_Float16)p1[2 * jj + 1]};
            f2.p[jj] = h2{(_Float16)p2[2 * jj], (_Float16)p2[2 * jj + 1]};
        }
        A0[t] = f0.h8; A1i[t] = f1.h8; A1h[t] = f2.h8;
    }

    // ---- per-lane constants over j=0..7 (h' = 8q + j) ----
    float wxs[8], b0s[8], wfc8[8];
#pragma unroll
    for (int j = 0; j < 8; ++j) {
        const int hh = 8 * q + j;
        wxs[j]  = Wih0[hh];
        b0s[j]  = bih0[hh] + bhh0[hh];
        wfc8[j] = Wfc[hh];
    }
    f32x4 c1t0, c1t1;   // layer-1 bias, rides as C of the Whh1 MFMA
#pragma unroll
    for (int r = 0; r < 4; ++r) {
        c1t0[r] = bih1[8 * q + r] + bhh1[8 * q + r];
        c1t1[r] = bih1[8 * q + 4 + r] + bhh1[8 * q + 4 + r];
    }

    // ---- initial h state as f16 B-fragments ----
    frag_u hb0, hb1;
    {
        const float* p0 = hstate + b * HH + 8 * q;
        const float* p1 = hstate + BB * HH + b * HH + 8 * q;
#pragma unroll
        for (int jj = 0; jj < 4; ++jj) {
            hb0.p[jj] = h2{(_Float16)p0[2 * jj], (_Float16)p0[2 * jj + 1]};
            hb1.p[jj] = h2{(_Float16)p1[2 * jj], (_Float16)p1[2 * jj + 1]};
        }
    }

    f32x4 dbp0, dbp1;   // pending bias1 + Whh1 . h1(s-2)

    const float4* xp = (const float4*)(x + (size_t)b * TT);
    float4 xc = xp[0];

    // ---- prologue: layer-0 step 0, and pending db for layer-1 step 0 ----
    {
        f32x4 c00, c01;
#pragma unroll
        for (int r = 0; r < 4; ++r) {
            c00[r] = fmaf(wxs[r], xc.x, b0s[r]);
            c01[r] = fmaf(wxs[4 + r], xc.x, b0s[4 + r]);
        }
        f32x4 d00 = MFMA16F(A0[0], hb0.h8, c00);
        f32x4 d01 = MFMA16F(A0[1], hb0.h8, c01);
        dbp0 = MFMA16F(A1h[0], hb1.h8, c1t0);
        dbp1 = MFMA16F(A1h[1], hb1.h8, c1t1);
        hb0.p[0] = tanh_pk(d00[0], d00[1]);
        hb0.p[1] = tanh_pk(d00[2], d00[3]);
        hb0.p[2] = tanh_pk(d01[0], d01[1]);
        hb0.p[3] = tanh_pk(d01[2], d01[3]);
    }

    // STEP: enter with hb0=h0(s-1), hb1=h1(s-2), dbp=b1+Whh1.h1(s-2).
    // Computes h1(s-1) and h0(s); refills dbp with b1+Whh1.h1(s-1).
#define STEP(XT)                                                              \
    {                                                                         \
        f32x4 d10 = MFMA16F(A1i[0], hb0.h8, dbp0);                            \
        f32x4 d11 = MFMA16F(A1i[1], hb0.h8, dbp1);                            \
        f32x4 c00, c01;                                                       \
        _Pragma("unroll")                                                     \
        for (int r = 0; r < 4; ++r) {                                         \
            c00[r] = fmaf(wxs[r], (XT), b0s[r]);                              \
            c01[r] = fmaf(wxs[4 + r], (XT), b0s[4 + r]);                      \
        }                                                                     \
        f32x4 d00 = MFMA16F(A0[0], hb0.h8, c00);                              \
        f32x4 d01 = MFMA16F(A0[1], hb0.h8, c01);                              \
        hb1.p[0] = tanh_pk(d10[0], d10[1]);                                   \
        hb1.p[1] = tanh_pk(d10[2], d10[3]);                                   \
        hb1.p[2] = tanh_pk(d11[0], d11[1]);                                   \
        hb1.p[3] = tanh_pk(d11[2], d11[3]);                                   \
        dbp0 = MFMA16F(A1h[0], hb1.h8, c1t0);                                 \
        dbp1 = MFMA16F(A1h[1], hb1.h8, c1t1);                                 \
        hb0.p[0] = tanh_pk(d00[0], d00[1]);                                   \
        hb0.p[1] = tanh_pk(d00[2], d00[3]);                                   \
        hb0.p[2] = tanh_pk(d01[0], d01[1]);                                   \
        hb0.p[3] = tanh_pk(d01[2], d01[3]);                                   \
    }

    // main loop: k = 0..126 handles s = 4k+1 .. 4k+4
    for (int k = 0; k < TT / 4 - 1; ++k) {
        float4 xn = xp[k + 1];
        STEP(xc.y);
        STEP(xc.z);
        STEP(xc.w);
        STEP(xn.x);
        xc = xn;
    }
    // s = 509, 510, 511
    STEP(xc.y);
    STEP(xc.z);
    STEP(xc.w);

    // tail: layer-1 step 511
    {
        f32x4 d10 = MFMA16F(A1i[0], hb0.h8, dbp0);
        f32x4 d11 = MFMA16F(A1i[1], hb0.h8, dbp1);
        hb1.p[0] = tanh_pk(d10[0], d10[1]);
        hb1.p[1] = tanh_pk(d10[2], d10[3]);
        hb1.p[2] = tanh_pk(d11[0], d11[1]);
        hb1.p[3] = tanh_pk(d11[2], d11[3]);
    }

    // ---- epilogue ----
    float hf0[8], hf1[8];
#pragma unroll
    for (int jj = 0; jj < 4; ++jj) {
        hf0[2 * jj]     = (float)hb0.p[jj].x;
        hf0[2 * jj + 1] = (float)hb0.p[jj].y;
        hf1[2 * jj]     = (float)hb1.p[jj].x;
        hf1[2 * jj + 1] = (float)hb1.p[jj].y;
    }
    float p = 0.f;
#pragma unroll
    for (int j = 0; j < 8; ++j) p = fmaf(wfc8[j], hf1[j], p);
    p += __shfl_xor(p, 16);
    p += __shfl_xor(p, 32);
    if (q == 0) out[b] = p + bfc[0];

#pragma unroll
    for (int j = 0; j < 8; ++j) {
        out[BB + b * HH + 8 * q + j]           = hf0[j];
        out[BB + BB * HH + b * HH + 8 * q + j] = hf1[j];
    }
}

extern "C" void kernel_launch(void* const* d_in, const int* in_sizes, int n_in,
                              void* d_out, int out_size, void* d_ws, size_t ws_size,
                              hipStream_t stream) {
    const float* x      = (const float*)d_in[0];
    const float* hstate = (const float*)d_in[1];
    const float* Wih0   = (const float*)d_in[2];
    const float* Whh0   = (const float*)d_in[3];
    const float* bih0   = (const float*)d_in[4];
    const float* bhh0   = (const float*)d_in[5];
    const float* Wih1   = (const float*)d_in[6];
    const float* Whh1   = (const float*)d_in[7];
    const float* bih1   = (const float*)d_in[8];
    const float* bhh1   = (const float*)d_in[9];
    const float* Wfc    = (const float*)d_in[10];
    const float* bfc    = (const float*)d_in[11];
    float* out = (float*)d_out;

    dim3 grid(BB / 16);  // 256 blocks x 1 wave, one 16-batch tile each
    dim3 block(64);
    hipLaunchKernelGGL(rnn2_mfma, grid, block, 0, stream,
                       x, hstate, Wih0, Whh0, bih0, bhh0,
                       Wih1, Whh1, bih1, bhh1, Wfc, bfc, out);
}